// Round 1
// 158.501 us; speedup vs baseline: 1.0644x; 1.0644x over previous
//
#include <hip/hip_runtime.h>
#include <hip/hip_bf16.h>
#include <math.h>

#define B 32
#define T 1024
#define AC 20
#define SE 16
#define H 64
#define NH 4
#define HD 16
#define NROW (B*T)      // 32768
#define BH (B*NH)       // 128
#define KS 2
#define NCHUNK (T/32)   // 32 chunks of 32 keys

typedef unsigned short u16;
typedef short short8 __attribute__((ext_vector_type(8)));
typedef float floatx4 __attribute__((ext_vector_type(4)));
typedef float f32x16 __attribute__((ext_vector_type(16)));
typedef unsigned int uintx4 __attribute__((ext_vector_type(4)));

// ---- workspace layout (float offsets) ----
#define F_QB   (BH*T*16/2)                   // bf16 tensor of BH*T*16 elems in float units
#define OFF_QB   0
#define OFF_KB   (OFF_QB + F_QB)
#define OFF_VT   (OFF_KB + F_QB)             // bf16 V2 [bh][g=t/16][d][t%16]
#define OFF_PART (OFF_VT + F_QB)             // f32 ctxT [64ch][NROW]
#define OFF_PARTL (OFF_PART + KS*BH*T*16)
#define OFF_ET   (OFF_PARTL + KS*BH*T)
#define OFF_AT   (OFF_ET + AC*NROW)
#define OFF_WF   (OFF_AT + AC*NROW)
#define OFF_PST  (OFF_WF + 5120)
#define OFF_ACC  (OFF_PST + 20*16*4)

// fused-weight sub-offsets inside wf
#define WF_WQ 0
#define WF_BQ 1024
#define WF_WK 1088
#define WF_BK 2368
#define WF_WV 2432
#define WF_BV 3712
#define WF_WO 3776
#define WF_BO 5056
#define WF_TOTAL 5076

__device__ __forceinline__ u16 bf16b(float a) {
    __hip_bfloat16 t = __float2bfloat16(a);
    u16 u; __builtin_memcpy(&u, &t, 2); return u;
}
__device__ __forceinline__ unsigned packbf(float a, float b) {
    return (unsigned)bf16b(a) | ((unsigned)bf16b(b) << 16);
}

// ---------------- K0: fuse weights ----------------
__global__ __launch_bounds__(256) void k_fuse(
    const float* __restrict__ Wq, const float* __restrict__ bq,
    const float* __restrict__ Wkv, const float* __restrict__ bkv,
    const float* __restrict__ in_w, const float* __restrict__ in_b,
    const float* __restrict__ out_w, const float* __restrict__ out_b,
    const float* __restrict__ proj_w, const float* __restrict__ proj_b,
    float* __restrict__ wf) {
    int idx = blockIdx.x * 256 + threadIdx.x;
    if (idx >= WF_TOTAL) return;
    if (idx < WF_BQ) {                       // WqF[i][j] (scale 0.25 folded)
        int i = idx >> 4, j = idx & 15;
        float s = 0.f;
        for (int m = 0; m < H; ++m) s += in_w[i*H + m] * Wq[m*SE + j];
        wf[idx] = 0.25f * s;
    } else if (idx < WF_WK) {                // bqF
        int i = idx - WF_BQ;
        float s = in_b[i];
        for (int m = 0; m < H; ++m) s += in_w[i*H + m] * bq[m];
        wf[idx] = 0.25f * s;
    } else if (idx < WF_BK) {                // WkF[i][j]
        int r = idx - WF_WK; int i = r / AC, j = r % AC;
        float s = 0.f;
        for (int m = 0; m < H; ++m) s += in_w[(H+i)*H + m] * Wkv[m*AC + j];
        wf[idx] = s;
    } else if (idx < WF_WV) {                // bkF
        int i = idx - WF_BK;
        float s = in_b[H + i];
        for (int m = 0; m < H; ++m) s += in_w[(H+i)*H + m] * bkv[m];
        wf[idx] = s;
    } else if (idx < WF_BV) {                // WvF[i][j]
        int r = idx - WF_WV; int i = r / AC, j = r % AC;
        float s = 0.f;
        for (int m = 0; m < H; ++m) s += in_w[(2*H+i)*H + m] * Wkv[(H+m)*AC + j];
        wf[idx] = s;
    } else if (idx < WF_WO) {                // bvF
        int i = idx - WF_BV;
        float s = in_b[2*H + i];
        for (int m = 0; m < H; ++m) s += in_w[(2*H+i)*H + m] * bkv[H + m];
        wf[idx] = s;
    } else if (idx < WF_BO) {                // WoF[c][d]
        int r = idx - WF_WO; int c = r >> 6, d = r & 63;
        float s = 0.f;
        for (int m = 0; m < H; ++m) s += proj_w[c*H + m] * out_w[m*H + d];
        wf[idx] = s;
    } else {                                 // boF
        int c = idx - WF_BO;
        float s = proj_b[c];
        for (int m = 0; m < H; ++m) s += proj_w[c*H + m] * out_b[m];
        wf[idx] = s;
    }
}

// ---------------- K1: fused QKV projection (wave-specialized, 12 sections/row) ----------------
// block = 192 threads = 16 rows x 12 sections; Q(4 heads), K, V
__global__ __launch_bounds__(192) void k_qkv(
    const float* __restrict__ sem, const float* __restrict__ acst,
    const float* __restrict__ wf,
    u16* __restrict__ Qb, u16* __restrict__ Kb, u16* __restrict__ Vtb) {
    const int tid = threadIdx.x;
    const int sec = tid >> 4, r = tid & 15;
    const int row = blockIdx.x * 16 + r;
    const int b = row >> 10, t = row & 1023;
    const int type = sec >> 2, h = sec & 3;
    float o[16];
    if (type == 0) {
        float s[SE];
        const float4* sp = (const float4*)(sem + (size_t)row * SE);
        #pragma unroll
        for (int i = 0; i < 4; ++i) {
            float4 v = sp[i];
            s[4*i] = v.x; s[4*i+1] = v.y; s[4*i+2] = v.z; s[4*i+3] = v.w;
        }
        const float* wq = wf + WF_WQ + h*16*SE;
        const float* bq = wf + WF_BQ + h*16;
        #pragma unroll
        for (int ii = 0; ii < 16; ++ii) {
            float acc = bq[ii];
            #pragma unroll
            for (int j = 0; j < 4; ++j) {
                float4 w4 = *(const float4*)(wq + ii*SE + 4*j);
                acc += s[4*j]*w4.x + s[4*j+1]*w4.y + s[4*j+2]*w4.z + s[4*j+3]*w4.w;
            }
            o[ii] = acc;
        }
        unsigned* dst = (unsigned*)(Qb + (((size_t)(b*NH + h))*T + t)*16);
        #pragma unroll
        for (int i = 0; i < 8; ++i) dst[i] = packbf(o[2*i], o[2*i+1]);
    } else {
        float a[AC];
        const float4* ap = (const float4*)(acst + (size_t)row * AC);
        #pragma unroll
        for (int i = 0; i < 5; ++i) {
            float4 v = ap[i];
            a[4*i] = v.x; a[4*i+1] = v.y; a[4*i+2] = v.z; a[4*i+3] = v.w;
        }
        const float* wb = wf + (type == 1 ? WF_WK : WF_WV) + h*16*AC;
        const float* bb = wf + (type == 1 ? WF_BK : WF_BV) + h*16;
        #pragma unroll
        for (int ii = 0; ii < 16; ++ii) {
            float acc = bb[ii];
            #pragma unroll
            for (int j = 0; j < 5; ++j) {
                float4 w4 = *(const float4*)(wb + ii*AC + 4*j);
                acc += a[4*j]*w4.x + a[4*j+1]*w4.y + a[4*j+2]*w4.z + a[4*j+3]*w4.w;
            }
            o[ii] = acc;
        }
        if (type == 1) {
            unsigned* dst = (unsigned*)(Kb + (((size_t)(b*NH + h))*T + t)*16);
            #pragma unroll
            for (int i = 0; i < 8; ++i) dst[i] = packbf(o[2*i], o[2*i+1]);
        } else {
            // V2 layout: [bh][g=t>>4][d][t&15] (16-key tiles, fragment-direct for MFMA A)
            u16* dst = Vtb + ((size_t)(b*NH + h)*64 + (t >> 4))*256 + (t & 15);
            #pragma unroll
            for (int d = 0; d < HD; ++d) dst[d*16] = bf16b(o[d]);
        }
    }
}

// ---------------- K2: MFMA flash attention, swapped 32x32, zero-LDS ----------------
// wave = 32 q-rows x full 1024 keys; block = 4 waves = 128 q; grid = 8*BH = 1024
// bh = blk & 127 so all 8 q-blocks of a (b,h) land on the same XCD (L2-local K/V).
__global__ __launch_bounds__(256, 4) void k_attn(
    const u16* __restrict__ Qb, const u16* __restrict__ Kb, const u16* __restrict__ Vtb,
    float* __restrict__ ctxT) {
    const int tid  = threadIdx.x;
    const int lane = tid & 63;
    const int wv   = tid >> 6;
    const int blk  = blockIdx.x;
    const int bh   = blk & 127;
    const int qblk = blk >> 7;
    const int b = bh >> 2, h = bh & 3;
    const int l31 = lane & 31, hi2 = lane >> 5, l15 = lane & 15;
    const int q0 = qblk*128 + wv*32;

    // B-fragment: Q^T[d][q], q = lane&31, d = 8*hi2 + j  (hoisted, scale folded)
    const short8 qf = *(const short8*)(Qb + ((size_t)bh*T + q0 + l31)*16 + 8*hi2);
    // A-fragment K: K[key][d], key = lane&31 (+32/chunk), d = 8*hi2 + j
    const u16* kp = Kb + ((size_t)bh*T + l31)*16 + 8*hi2;
    // A-fragment V^T: rows 16-31 duplicate rows 0-15 (harmless dup outputs)
    const u16* vp = Vtb + (size_t)bh*16384 + l15*16 + 8*hi2;

    f32x16 acc = {0.f,0.f,0.f,0.f,0.f,0.f,0.f,0.f,0.f,0.f,0.f,0.f,0.f,0.f,0.f,0.f};
    const f32x16 z16 = {0.f,0.f,0.f,0.f,0.f,0.f,0.f,0.f,0.f,0.f,0.f,0.f,0.f,0.f,0.f,0.f};
    float ls = 0.f;

    short8 kf = *(const short8*)kp;
    short8 va = *(const short8*)vp;
    short8 vb = *(const short8*)(vp + 256);
    #pragma unroll 4
    for (int ch = 0; ch < NCHUNK; ++ch) {
        const int nx = (ch < NCHUNK-1) ? ch + 1 : ch;   // depth-1 prefetch
        short8 kf_n = *(const short8*)(kp + (size_t)nx*512);
        short8 va_n = *(const short8*)(vp + (size_t)nx*512);
        short8 vb_n = *(const short8*)(vp + (size_t)nx*512 + 256);

        // scores^T[key][q]: C col = q (lane-local), rows = key-set (r&3)+8*(r>>2)+4*hi2
        f32x16 sc = __builtin_amdgcn_mfma_f32_32x32x16_bf16(kf, qf, z16, 0, 0, 0);
        float p[16];
        #pragma unroll
        for (int r = 0; r < 16; ++r) p[r] = __expf(sc[r]);
        #pragma unroll
        for (int r = 0; r < 16; ++r) ls += p[r];

        // pack P to bf16 pairs; k of p[r] = (r&3) + 8*(r>>2) + 4*hi2
        unsigned u0 = packbf(p[0],  p[1]);   // lo:(k0,k1)   hi:(k4,k5)
        unsigned u1 = packbf(p[2],  p[3]);   // lo:(k2,k3)   hi:(k6,k7)
        unsigned u2 = packbf(p[4],  p[5]);   // lo:(k8,k9)   hi:(k12,k13)
        unsigned u3 = packbf(p[6],  p[7]);   // lo:(k10,k11) hi:(k14,k15)
        unsigned u4 = packbf(p[8],  p[9]);   // lo:(k16,k17) hi:(k20,k21)
        unsigned u5 = packbf(p[10], p[11]);  // lo:(k18,k19) hi:(k22,k23)
        unsigned u6 = packbf(p[12], p[13]);  // lo:(k24,k25) hi:(k28,k29)
        unsigned u7 = packbf(p[14], p[15]);  // lo:(k26,k27) hi:(k30,k31)
        // in-register transpose across lane halves (T12): after swap,
        // u0..u3 = B-frag keys 0-15, u4..u7 = B-frag keys 16-31
        asm("v_permlane32_swap_b32 %0, %1" : "+v"(u2), "+v"(u0));
        asm("v_permlane32_swap_b32 %0, %1" : "+v"(u3), "+v"(u1));
        asm("v_permlane32_swap_b32 %0, %1" : "+v"(u6), "+v"(u4));
        asm("v_permlane32_swap_b32 %0, %1" : "+v"(u7), "+v"(u5));
        uintx4 t1 = {u0, u1, u2, u3};
        uintx4 t2 = {u4, u5, u6, u7};
        short8 pf1 = __builtin_bit_cast(short8, t1);
        short8 pf2 = __builtin_bit_cast(short8, t2);

        acc = __builtin_amdgcn_mfma_f32_32x32x16_bf16(va, pf1, acc, 0, 0, 0);
        acc = __builtin_amdgcn_mfma_f32_32x32x16_bf16(vb, pf2, acc, 0, 0, 0);

        kf = kf_n; va = va_n; vb = vb_n;
    }

    // lanes l and l^32 hold complementary key halves of the same q
    ls += __shfl_xor(ls, 32);
    const float inv = 1.f / ls;
    const int row = b*T + q0 + l31;
    #pragma unroll
    for (int r = 0; r < 8; ++r) {           // regs 8-15 are duplicate d rows
        const int d = (r & 3) + 8*(r >> 2) + 4*hi2;
        ctxT[(size_t)(h*16 + d)*NROW + row] = acc[r] * inv;
    }
}

// ---------------- K3: output proj + residual (64 rows/block) ----------------
#define CSTR 65
__global__ __launch_bounds__(256) void k_proj(
    const float* __restrict__ ctxT, const float* __restrict__ acst,
    const float* __restrict__ wf, const float* __restrict__ rlogit,
    float* __restrict__ enhT, float* __restrict__ aT) {
    __shared__ float ctxs[64*CSTR];                     // stride-65 conflict-free
    __shared__ __align__(16) float wsm[AC*H + AC];      // 5.2 KB
    const int tid = threadIdx.x;
    for (int i = tid; i < AC*H + AC; i += 256) wsm[i] = wf[WF_WO + i];
    // ---- phase 1: load normalized ctx^T chunk into LDS (coalesced) ----
    const int row0 = blockIdx.x * 64;
    for (int i = tid; i < 64*64; i += 256) {
        int ch = i >> 6, rr = i & 63;
        ctxs[rr*CSTR + ch] = ctxT[(size_t)ch*NROW + row0 + rr];
    }
    __syncthreads();
    // ---- phase 2: 5 output channels per thread ----
    const int r = tid & 63, cg = tid >> 6;
    const int row = row0 + r;
    float c64[H];
    #pragma unroll
    for (int k = 0; k < H; ++k) c64[k] = ctxs[r*CSTR + k];
    float sg = 1.f / (1.f + __expf(-rlogit[0]));
    #pragma unroll
    for (int j = 0; j < 5; ++j) {
        int ch = cg*5 + j;
        float s = wsm[AC*H + ch];
        const float4* w4 = (const float4*)(wsm + ch*H);
        #pragma unroll
        for (int k = 0; k < 16; ++k) {
            float4 w = w4[k];
            s += c64[4*k]*w.x + c64[4*k+1]*w.y + c64[4*k+2]*w.z + c64[4*k+3]*w.w;
        }
        float a = acst[(size_t)row*AC + ch];
        float e = a + sg * s;
        enhT[(size_t)ch * NROW + row] = e;
        aT[(size_t)ch * NROW + row]  = a;
    }
}

// ---------------- K4: per-channel partial stats ----------------
__global__ __launch_bounds__(256) void k_stats1(
    const float* __restrict__ aT, const float* __restrict__ enhT,
    float* __restrict__ pst) {
    int c = blockIdx.x >> 4, sl = blockIdx.x & 15;
    int base = sl * (NROW/16);
    const float* ac = aT  + (size_t)c*NROW + base;
    const float* ec = enhT + (size_t)c*NROW + base;
    float sa = 0.f, qa = 0.f, se = 0.f, qe = 0.f;
    for (int r = threadIdx.x; r < NROW/16; r += 256) {
        float a = ac[r]; sa += a; qa += a*a;
        float e = ec[r]; se += e; qe += e*e;
    }
    #pragma unroll
    for (int off = 32; off > 0; off >>= 1) {
        sa += __shfl_down(sa, off);
        qa += __shfl_down(qa, off);
        se += __shfl_down(se, off);
        qe += __shfl_down(qe, off);
    }
    __shared__ float rs[4][4];
    int w = threadIdx.x >> 6;
    if ((threadIdx.x & 63) == 0) { rs[w][0] = sa; rs[w][1] = qa; rs[w][2] = se; rs[w][3] = qe; }
    __syncthreads();
    if (threadIdx.x == 0) {
        float A = 0.f, QA = 0.f, E = 0.f, QE = 0.f;
        for (int i = 0; i < 4; ++i) { A += rs[i][0]; QA += rs[i][1]; E += rs[i][2]; QE += rs[i][3]; }
        float* d = pst + (size_t)(c*16 + sl)*4;
        d[0] = A; d[1] = QA; d[2] = E; d[3] = QE;
    }
}

// ---------------- K5: combine stats + std-correction + LayerNorm ----------------
__global__ __launch_bounds__(128) void k_final(
    const float* __restrict__ enhT, const float* __restrict__ pst,
    const float* __restrict__ gamma, const float* __restrict__ beta,
    float* __restrict__ out) {
    __shared__ float acs[80];
    const int tx = threadIdx.x;
    if (tx < 80) {
        int c = tx >> 2, j = tx & 3;
        float s = 0.f;
        #pragma unroll
        for (int sl = 0; sl < 16; ++sl) s += pst[(size_t)(c*16 + sl)*4 + j];
        acs[tx] = s;
    }
    __syncthreads();
    int row = blockIdx.x * 128 + tx;
    const float Nf = (float)NROW;
    float ef[AC];
    #pragma unroll
    for (int c = 0; c < AC; ++c) {
        float sa = acs[c*4+0], qa = acs[c*4+1];
        float se = acs[c*4+2], qe = acs[c*4+3];
        float mu  = sa / Nf;
        float va  = (qa - sa*sa/Nf) / (Nf - 1.f);
        float sda = sqrtf(fmaxf(va, 0.f));
        float osd = sda + 1e-8f;
        float ve  = (qe - se*se/Nf) / (Nf - 1.f);
        float sde = sqrtf(fmaxf(ve, 0.f));
        float ratio = (sde / osd) / (sda / osd + 1e-8f);
        float corr  = (ratio < 0.4f) ? (0.4f / ratio) : 1.f;
        float e = enhT[(size_t)c * NROW + row];
        ef[c] = (e - mu) * corr + mu;
    }
    float m = 0.f;
    #pragma unroll
    for (int c = 0; c < AC; ++c) m += ef[c];
    m *= (1.f / AC);
    float v = 0.f;
    #pragma unroll
    for (int c = 0; c < AC; ++c) { float d = ef[c] - m; v += d*d; }
    v *= (1.f / AC);
    float inv = rsqrtf(v + 1e-5f);
    float o[AC];
    #pragma unroll
    for (int c = 0; c < AC; ++c) o[c] = (ef[c] - m) * inv * gamma[c] + beta[c];
    float4* op = (float4*)(out + (size_t)row * AC);
    #pragma unroll
    for (int i = 0; i < 5; ++i)
        op[i] = make_float4(o[4*i], o[4*i+1], o[4*i+2], o[4*i+3]);
}

extern "C" void kernel_launch(void* const* d_in, const int* in_sizes, int n_in,
                              void* d_out, int out_size, void* d_ws, size_t ws_size,
                              hipStream_t stream) {
    (void)in_sizes; (void)n_in; (void)out_size; (void)ws_size;
    const float* acoustic = (const float*)d_in[0];
    const float* semantic = (const float*)d_in[1];
    const float* Wq     = (const float*)d_in[2];
    const float* bq     = (const float*)d_in[3];
    const float* Wkv    = (const float*)d_in[4];
    const float* bkv    = (const float*)d_in[5];
    const float* in_w   = (const float*)d_in[6];
    const float* in_b   = (const float*)d_in[7];
    const float* out_w  = (const float*)d_in[8];
    const float* out_b  = (const float*)d_in[9];
    const float* proj_w = (const float*)d_in[10];
    const float* proj_b = (const float*)d_in[11];
    const float* rlogit = (const float*)d_in[12];
    const float* gamma  = (const float*)d_in[13];
    const float* beta   = (const float*)d_in[14];
    float* ws = (float*)d_ws;
    u16* Qb  = (u16*)(ws + OFF_QB);
    u16* Kb  = (u16*)(ws + OFF_KB);
    u16* Vtb = (u16*)(ws + OFF_VT);
    float* ctxT  = ws + OFF_PART;
    float* enhT  = ws + OFF_ET;
    float* aT    = ws + OFF_AT;
    float* wf    = ws + OFF_WF;
    float* pst   = ws + OFF_PST;
    float* out = (float*)d_out;

    k_fuse<<<(WF_TOTAL + 255)/256, 256, 0, stream>>>(Wq, bq, Wkv, bkv, in_w, in_b,
                                                     out_w, out_b, proj_w, proj_b, wf);
    k_qkv<<<NROW/16, 192, 0, stream>>>(semantic, acoustic, wf, Qb, Kb, Vtb);
    k_attn<<<8*BH, 256, 0, stream>>>(Qb, Kb, Vtb, ctxT);
    k_proj<<<NROW/64, 256, 0, stream>>>(ctxT, acoustic, wf, rlogit, enhT, aT);
    k_stats1<<<AC*16, 256, 0, stream>>>(aT, enhT, pst);
    k_final<<<NROW/128, 128, 0, stream>>>(enhT, pst, gamma, beta, out);
}